// Round 1
// baseline (406.758 us; speedup 1.0000x reference)
//
#include <hip/hip_runtime.h>
#include <math.h>

#define NN 100000
#define NE 1600000

// ---------------- kernels ----------------

__global__ void deg_kernel(const int* __restrict__ col, float* __restrict__ deg, int E) {
    int e = blockIdx.x * blockDim.x + threadIdx.x;
    if (e < E) atomicAdd(&deg[col[e]], 1.0f);
}

__global__ void dis_kernel(float* __restrict__ deg, int N) {
    int i = blockIdx.x * blockDim.x + threadIdx.x;
    if (i < N) {
        float d = deg[i];
        deg[i] = (d > 0.0f) ? rsqrtf(d) : 0.0f;   // deg buffer becomes deg^-1/2
    }
}

// layer-1 aggregate of RAW features (S @ x): 2 floats per edge
__global__ void scatter1_kernel(const int* __restrict__ row, const int* __restrict__ col,
                                const float* __restrict__ dis, const float* __restrict__ x,
                                float* __restrict__ aggx, int E) {
    int e = blockIdx.x * blockDim.x + threadIdx.x;
    if (e < E) {
        int r = row[e], c = col[e];
        float nrm = dis[r] * dis[c];
        float x0 = x[2 * r], x1 = x[2 * r + 1];
        atomicAdd(&aggx[2 * c],     x0 * nrm);
        atomicAdd(&aggx[2 * c + 1], x1 * nrm);
    }
}

// per-node: h = relu(aggx @ W1 + b1); z = h @ W2   (h never materialized)
__global__ void node1_kernel(const float* __restrict__ aggx,
                             const float* __restrict__ W1, const float* __restrict__ b1,
                             const float* __restrict__ W2,
                             float* __restrict__ z, int N) {
    __shared__ float sW0[64], sW1[64], sb[64], sW2[64];
    int t = threadIdx.x;
    if (t < 64) {
        sW0[t] = W1[t];          // W1[0][j]
        sW1[t] = W1[64 + t];     // W1[1][j]
        sb[t]  = b1[t];
        sW2[t] = W2[t];
    }
    __syncthreads();
    int i = blockIdx.x * blockDim.x + t;
    if (i < N) {
        float a0 = aggx[2 * i], a1 = aggx[2 * i + 1];
        float acc = 0.0f;
#pragma unroll
        for (int j = 0; j < 64; ++j) {
            float h = fmaf(a0, sW0[j], fmaf(a1, sW1[j], sb[j]));
            h = fmaxf(h, 0.0f);
            acc = fmaf(h, sW2[j], acc);
        }
        z[i] = acc;
    }
}

// layer-2 aggregate of the per-node scalar z
__global__ void scatter2_kernel(const int* __restrict__ row, const int* __restrict__ col,
                                const float* __restrict__ dis, const float* __restrict__ z,
                                float* __restrict__ agg2, int E) {
    int e = blockIdx.x * blockDim.x + threadIdx.x;
    if (e < E) {
        int r = row[e], c = col[e];
        float nrm = dis[r] * dis[c];
        atomicAdd(&agg2[c], z[r] * nrm);
    }
}

__global__ void out_kernel(const float* __restrict__ agg2, const float* __restrict__ b2,
                           float* __restrict__ out, int N) {
    int i = blockIdx.x * blockDim.x + threadIdx.x;
    if (i < N) out[i] = fmaxf(agg2[i] + b2[0], 0.0f);
}

// ---------------- launch ----------------

extern "C" void kernel_launch(void* const* d_in, const int* in_sizes, int n_in,
                              void* d_out, int out_size, void* d_ws, size_t ws_size,
                              hipStream_t stream) {
    const float* x   = (const float*)d_in[0];
    const int*   ei  = (const int*)d_in[1];   // [2, E] int32: row then col
    const float* W1  = (const float*)d_in[2];
    const float* b1  = (const float*)d_in[3];
    const float* W2  = (const float*)d_in[4];
    const float* b2  = (const float*)d_in[5];
    float* out = (float*)d_out;

    const int N = NN;
    const int E = NE;
    const int* row = ei;
    const int* col = ei + E;

    // workspace layout (floats): [deg/dis N | aggx 2N | agg2 N | z N]
    float* ws   = (float*)d_ws;
    float* deg  = ws;            // N
    float* aggx = ws + N;        // 2N
    float* agg2 = ws + 3 * N;    // N
    float* z    = ws + 4 * N;    // N

    // zero deg + aggx + agg2 (first 4N floats) — ws is poisoned 0xAA each call
    hipMemsetAsync(ws, 0, (size_t)4 * N * sizeof(float), stream);

    const int BT = 256;
    dim3 gE((E + BT - 1) / BT), gN((N + BT - 1) / BT), b(BT);

    deg_kernel<<<gE, b, 0, stream>>>(col, deg, E);
    dis_kernel<<<gN, b, 0, stream>>>(deg, N);
    scatter1_kernel<<<gE, b, 0, stream>>>(row, col, deg, x, aggx, E);
    node1_kernel<<<gN, b, 0, stream>>>(aggx, W1, b1, W2, z, N);
    scatter2_kernel<<<gE, b, 0, stream>>>(row, col, deg, z, agg2, E);
    out_kernel<<<gN, b, 0, stream>>>(agg2, b2, out, N);
}

// Round 2
// 166.266 us; speedup vs baseline: 2.4464x; 2.4464x over previous
//
#include <hip/hip_runtime.h>
#include <math.h>

#define NN 100000
#define NE 1600000
#define BKT_SHIFT 8
#define BKT 256                 // nodes per bucket
#define NB 391                  // ceil(NN / BKT)
#define SCAN_T 512
#define EPB 4096                // edges per block in partition
#define NPB 391                 // ceil(NE / EPB)

// ---------- A1: bucket histogram (LDS hist, merge to global) ----------
__global__ void bucket_hist_kernel(const int* __restrict__ col, int* __restrict__ bcnt) {
    __shared__ int h[NB];
    for (int i = threadIdx.x; i < NB; i += blockDim.x) h[i] = 0;
    __syncthreads();
    int stride = gridDim.x * blockDim.x;
    for (int e = blockIdx.x * blockDim.x + threadIdx.x; e < NE; e += stride)
        atomicAdd(&h[col[e] >> BKT_SHIFT], 1);
    __syncthreads();
    for (int i = threadIdx.x; i < NB; i += blockDim.x)
        if (h[i]) atomicAdd(&bcnt[i], h[i]);
}

// ---------- A2: exclusive scan over NB bucket counts (1 block) ----------
__global__ void scan_kernel(const int* __restrict__ bcnt, int* __restrict__ start,
                            int* __restrict__ cursor) {
    __shared__ int s[SCAN_T];
    int t = threadIdx.x;
    int v = (t < NB) ? bcnt[t] : 0;
    s[t] = v;
    __syncthreads();
    for (int off = 1; off < SCAN_T; off <<= 1) {
        int u = (t >= off) ? s[t - off] : 0;
        __syncthreads();
        s[t] += u;
        __syncthreads();
    }
    if (t < NB) { int ex = s[t] - v; start[t] = ex; cursor[t] = ex; }
    if (t == 0) start[NB] = s[NB - 1];
}

// ---------- A3: reorder edges into bucket-contiguous packed records ----------
// record = (row << 8) | col_local   (row < 2^17, col_local < 256)
__global__ void reorder_kernel(const int* __restrict__ row, const int* __restrict__ col,
                               int* __restrict__ cursor, unsigned* __restrict__ packed) {
    __shared__ int h[NB];
    __shared__ int base[NB];
    int t = threadIdx.x;
    for (int i = t; i < NB; i += blockDim.x) h[i] = 0;
    __syncthreads();
    int e0 = blockIdx.x * EPB;
    int e1 = min(e0 + EPB, NE);
    for (int e = e0 + t; e < e1; e += blockDim.x)
        atomicAdd(&h[col[e] >> BKT_SHIFT], 1);
    __syncthreads();
    for (int i = t; i < NB; i += blockDim.x) {
        int c = h[i];
        base[i] = c ? atomicAdd(&cursor[i], c) : 0;
    }
    __syncthreads();
    for (int i = t; i < NB; i += blockDim.x) h[i] = 0;
    __syncthreads();
    for (int e = e0 + t; e < e1; e += blockDim.x) {
        int c = col[e];
        int b = c >> BKT_SHIFT;
        int rank = atomicAdd(&h[b], 1);
        packed[base[b] + rank] = ((unsigned)row[e] << BKT_SHIFT) | (unsigned)(c & (BKT - 1));
    }
}

// ---------- B0: per-bucket degree hist -> dis, y2 = x * dis ----------
__global__ void bucket_deg_kernel(const unsigned* __restrict__ packed, const int* __restrict__ start,
                                  const float* __restrict__ x,
                                  float* __restrict__ dis, float2* __restrict__ y2) {
    __shared__ int cnt[BKT];
    int t = threadIdx.x;           // blockDim == BKT == 256
    cnt[t] = 0;
    __syncthreads();
    int b = blockIdx.x;
    int e0 = start[b], e1 = start[b + 1];
    for (int e = e0 + t; e < e1; e += 256)
        atomicAdd(&cnt[packed[e] & (BKT - 1)], 1);
    __syncthreads();
    int node = (b << BKT_SHIFT) + t;
    if (node < NN) {
        int d = cnt[t];
        float dv = (d > 0) ? rsqrtf((float)d) : 0.0f;
        dis[node] = dv;
        y2[node] = make_float2(x[2 * node] * dv, x[2 * node + 1] * dv);
    }
}

// ---------- B1: layer-1 aggregate in LDS + fused node MLP -> z2 = (h@W2)*dis ----------
__global__ void agg1_kernel(const unsigned* __restrict__ packed, const int* __restrict__ start,
                            const float2* __restrict__ y2, const float* __restrict__ dis,
                            const float* __restrict__ W1, const float* __restrict__ b1,
                            const float* __restrict__ W2, float* __restrict__ z2) {
    __shared__ float ax[BKT], ay[BKT];
    __shared__ float sW0[64], sW1[64], sb1[64], sW2[64];
    int t = threadIdx.x;
    ax[t] = 0.0f; ay[t] = 0.0f;
    if (t < 64) { sW0[t] = W1[t]; sW1[t] = W1[64 + t]; sb1[t] = b1[t]; sW2[t] = W2[t]; }
    __syncthreads();
    int b = blockIdx.x;
    int e0 = start[b], e1 = start[b + 1];
    for (int e = e0 + t; e < e1; e += 256) {
        unsigned p = packed[e];
        float2 v = y2[p >> BKT_SHIFT];
        int cl = p & (BKT - 1);
        atomicAdd(&ax[cl], v.x);
        atomicAdd(&ay[cl], v.y);
    }
    __syncthreads();
    int node = (b << BKT_SHIFT) + t;
    if (node < NN) {
        float dv = dis[node];
        float a0 = ax[t] * dv, a1 = ay[t] * dv;
        float acc = 0.0f;
#pragma unroll
        for (int j = 0; j < 64; ++j) {
            float h = fmaf(a0, sW0[j], fmaf(a1, sW1[j], sb1[j]));
            acc = fmaf(fmaxf(h, 0.0f), sW2[j], acc);
        }
        z2[node] = acc * dv;
    }
}

// ---------- B2: layer-2 aggregate in LDS + bias + relu -> out ----------
__global__ void agg2_kernel(const unsigned* __restrict__ packed, const int* __restrict__ start,
                            const float* __restrict__ z2, const float* __restrict__ dis,
                            const float* __restrict__ b2, float* __restrict__ out) {
    __shared__ float acc[BKT];
    int t = threadIdx.x;
    acc[t] = 0.0f;
    __syncthreads();
    int b = blockIdx.x;
    int e0 = start[b], e1 = start[b + 1];
    for (int e = e0 + t; e < e1; e += 256) {
        unsigned p = packed[e];
        atomicAdd(&acc[p & (BKT - 1)], z2[p >> BKT_SHIFT]);
    }
    __syncthreads();
    int node = (b << BKT_SHIFT) + t;
    if (node < NN)
        out[node] = fmaxf(fmaf(dis[node], acc[t], b2[0]), 0.0f);
}

// ---------- launch ----------
extern "C" void kernel_launch(void* const* d_in, const int* in_sizes, int n_in,
                              void* d_out, int out_size, void* d_ws, size_t ws_size,
                              hipStream_t stream) {
    const float* x  = (const float*)d_in[0];
    const int*   ei = (const int*)d_in[1];     // [2, E] int32: row then col
    const float* W1 = (const float*)d_in[2];
    const float* b1 = (const float*)d_in[3];
    const float* W2 = (const float*)d_in[4];
    const float* b2 = (const float*)d_in[5];
    float* out = (float*)d_out;

    const int* row = ei;
    const int* col = ei + NE;

    // workspace layout
    float2*   y2     = (float2*)d_ws;              // NN float2 (800 KB)
    unsigned* packed = (unsigned*)(y2 + NN);       // NE uint   (6.4 MB)
    float*    dis    = (float*)(packed + NE);      // NN float
    float*    z2     = dis + NN;                   // NN float
    int*      bcnt   = (int*)(z2 + NN);            // NB
    int*      start  = bcnt + NB;                  // NB+1
    int*      cursor = start + NB + 1;             // NB

    hipMemsetAsync(bcnt, 0, NB * sizeof(int), stream);

    bucket_hist_kernel<<<512, 256, 0, stream>>>(col, bcnt);
    scan_kernel<<<1, SCAN_T, 0, stream>>>(bcnt, start, cursor);
    reorder_kernel<<<NPB, 256, 0, stream>>>(row, col, cursor, packed);
    bucket_deg_kernel<<<NB, 256, 0, stream>>>(packed, start, x, dis, y2);
    agg1_kernel<<<NB, 256, 0, stream>>>(packed, start, y2, dis, W1, b1, W2, z2);
    agg2_kernel<<<NB, 256, 0, stream>>>(packed, start, z2, dis, b2, out);
}

// Round 3
// 149.506 us; speedup vs baseline: 2.7207x; 1.1121x over previous
//
#include <hip/hip_runtime.h>
#include <math.h>

#define NN 100000
#define NE 1600000
#define NB 391          // target buckets of 256 nodes
#define EPB 4096        // edges per reorder chunk
#define NPB 391         // ceil(NE/EPB)
#define CAP 5120        // sortb LDS staging capacity (avg run 4096, sd 64)

// ---------- K1: coarse bucket histogram ----------
__global__ void hist_kernel(const int* __restrict__ col, int* __restrict__ bcnt) {
    __shared__ int h[NB];
    for (int i = threadIdx.x; i < NB; i += blockDim.x) h[i] = 0;
    __syncthreads();
    int stride = gridDim.x * blockDim.x;
    for (int e = blockIdx.x * blockDim.x + threadIdx.x; e < NE; e += stride)
        atomicAdd(&h[col[e] >> 8], 1);
    __syncthreads();
    for (int i = threadIdx.x; i < NB; i += blockDim.x)
        if (h[i]) atomicAdd(&bcnt[i], h[i]);
}

// ---------- K2: exclusive scan of NB bucket counts ----------
__global__ void scan_kernel(const int* __restrict__ bcnt, int* __restrict__ start,
                            int* __restrict__ cursor) {
    __shared__ int s[512];
    int t = threadIdx.x;
    int v = (t < NB) ? bcnt[t] : 0;
    s[t] = v;
    __syncthreads();
    for (int off = 1; off < 512; off <<= 1) {
        int u = (t >= off) ? s[t - off] : 0;
        __syncthreads();
        s[t] += u;
        __syncthreads();
    }
    if (t < NB) { start[t] = s[t] - v; cursor[t] = s[t] - v; }
    if (t == NB - 1) start[NB] = s[t];
}

// ---------- K3: reorder edges into bucket runs (LDS-staged, coalesced out) ----------
// packed record = (row << 8) | (col & 255)
__global__ void reorder_kernel(const int* __restrict__ row, const int* __restrict__ col,
                               int* __restrict__ cursor, unsigned* __restrict__ packed) {
    __shared__ int h[392], lb[392], gb[392];
    __shared__ int s[256];
    __shared__ unsigned st[EPB];
    __shared__ unsigned short sbkt[EPB];
    int t = threadIdx.x;
    int e0 = blockIdx.x * EPB;
    int n = min(EPB, NE - e0);

    for (int i = t; i < 392; i += 256) h[i] = 0;
    __syncthreads();

    unsigned pk[16]; int bb[16];
#pragma unroll
    for (int u = 0; u < 16; ++u) {
        int i = u * 256 + t;
        if (i < n) {
            int r = row[e0 + i], c = col[e0 + i];
            pk[u] = ((unsigned)r << 8) | (unsigned)(c & 255);
            bb[u] = c >> 8;
        } else bb[u] = -1;
    }
#pragma unroll
    for (int u = 0; u < 16; ++u)
        if (bb[u] >= 0) atomicAdd(&h[bb[u]], 1);
    __syncthreads();

    // exclusive scan of h[0..391] (pairs per thread)
    int a0 = h[2 * t], a1 = h[2 * t + 1];
    int pv = (t < 196) ? (a0 + a1) : 0;
    s[t] = pv;
    __syncthreads();
    for (int off = 1; off < 256; off <<= 1) {
        int u = (t >= off) ? s[t - off] : 0;
        __syncthreads();
        s[t] += u;
        __syncthreads();
    }
    int pex = s[t] - pv;
    lb[2 * t] = pex;
    lb[2 * t + 1] = pex + a0;
    // claim global space per bucket
    for (int b = t; b < NB; b += 256) {
        int c = h[b];
        gb[b] = c ? atomicAdd(&cursor[b], c) : 0;
    }
    __syncthreads();
    for (int i = t; i < 392; i += 256) h[i] = 0;   // reuse as rank counters
    __syncthreads();

#pragma unroll
    for (int u = 0; u < 16; ++u) {
        if (bb[u] >= 0) {
            int r = atomicAdd(&h[bb[u]], 1);
            int idx = lb[bb[u]] + r;
            st[idx] = pk[u];
            sbkt[idx] = (unsigned short)bb[u];
        }
    }
    __syncthreads();
    for (int i = t; i < n; i += 256) {
        int b = sbkt[i];
        packed[gb[b] + (i - lb[b])] = st[i];
    }
}

// ---------- K4: per-bucket counting sort -> CSR + degrees + dis + y2 ----------
__global__ void sortb_kernel(const unsigned* __restrict__ packed, const int* __restrict__ start,
                             const float2* __restrict__ x2,
                             unsigned* __restrict__ srow, int* __restrict__ node_begin,
                             float* __restrict__ dis, float2* __restrict__ y2) {
    __shared__ int cnt[256], scn[256], rk[256], sexA[256];
    __shared__ unsigned st[CAP];
    __shared__ unsigned srt[CAP];
    int t = threadIdx.x;
    int b = blockIdx.x;
    int s0 = start[b], s1 = start[b + 1];
    int L = s1 - s0;

    cnt[t] = 0; rk[t] = 0;
    __syncthreads();
    for (int i = t; i < L; i += 256) {
        unsigned p = packed[s0 + i];
        if (i < CAP) st[i] = p;
        atomicAdd(&cnt[p & 255u], 1);
    }
    __syncthreads();
    // inclusive scan of cnt
    int v = cnt[t];
    scn[t] = v;
    __syncthreads();
    for (int off = 1; off < 256; off <<= 1) {
        int u = (t >= off) ? scn[t - off] : 0;
        __syncthreads();
        scn[t] += u;
        __syncthreads();
    }
    int sex = scn[t] - v;
    sexA[t] = sex;
    __syncthreads();

    // per-node outputs
    int node = (b << 8) + t;
    if (node < NN) {
        float dv = (v > 0) ? rsqrtf((float)v) : 0.0f;
        dis[node] = dv;
        float2 xv = x2[node];
        y2[node] = make_float2(xv.x * dv, xv.y * dv);
        node_begin[node] = s0 + sex;
    } else if (node == NN) {
        node_begin[NN] = s0 + sex;
    }

    if (L <= CAP) {
        for (int i = t; i < L; i += 256) {
            unsigned p = st[i];
            int cl = p & 255u;
            int r = atomicAdd(&rk[cl], 1);
            srt[sexA[cl] + r] = p >> 8;
        }
        __syncthreads();
        for (int i = t; i < L; i += 256) srow[s0 + i] = srt[i];
    } else {
        // safety fallback (never triggers for this input): direct scatter
        for (int i = t; i < L; i += 256) {
            unsigned p = packed[s0 + i];
            int cl = p & 255u;
            int r = atomicAdd(&rk[cl], 1);
            srow[s0 + sexA[cl] + r] = p >> 8;
        }
    }
}

// ---------- K5: conv1 CSR sum + fused MLP -> z2 ----------
__global__ void conv1_kernel(const unsigned* __restrict__ srow, const int* __restrict__ node_begin,
                             const float2* __restrict__ y2, const float* __restrict__ dis,
                             const float* __restrict__ W1, const float* __restrict__ b1,
                             const float* __restrict__ W2, float* __restrict__ z2) {
    __shared__ float sW0[64], sW1[64], sb1[64], sW2[64];
    int t = threadIdx.x;
    if (t < 64) { sW0[t] = W1[t]; sW1[t] = W1[64 + t]; sb1[t] = b1[t]; sW2[t] = W2[t]; }
    __syncthreads();
    int n = blockIdx.x * blockDim.x + t;
    if (n >= NN) return;
    int beg = node_begin[n], end = node_begin[n + 1];
    float sx0 = 0.f, sy0 = 0.f, sx1 = 0.f, sy1 = 0.f;
    int k = beg;
    for (; k + 1 < end; k += 2) {
        unsigned r0 = srow[k], r1 = srow[k + 1];
        float2 v0 = y2[r0], v1 = y2[r1];
        sx0 += v0.x; sy0 += v0.y;
        sx1 += v1.x; sy1 += v1.y;
    }
    if (k < end) { float2 v = y2[srow[k]]; sx0 += v.x; sy0 += v.y; }
    float dv = dis[n];
    float a0 = (sx0 + sx1) * dv, a1 = (sy0 + sy1) * dv;
    float acc = 0.0f;
#pragma unroll
    for (int j = 0; j < 64; ++j) {
        float h = fmaf(a0, sW0[j], fmaf(a1, sW1[j], sb1[j]));
        acc = fmaf(fmaxf(h, 0.0f), sW2[j], acc);
    }
    z2[n] = acc * dv;
}

// ---------- K6: conv2 CSR sum + bias + relu -> out ----------
__global__ void conv2_kernel(const unsigned* __restrict__ srow, const int* __restrict__ node_begin,
                             const float* __restrict__ z2, const float* __restrict__ dis,
                             const float* __restrict__ b2, float* __restrict__ out) {
    int n = blockIdx.x * blockDim.x + threadIdx.x;
    if (n >= NN) return;
    int beg = node_begin[n], end = node_begin[n + 1];
    float s0 = 0.f, s1 = 0.f;
    int k = beg;
    for (; k + 1 < end; k += 2) {
        float v0 = z2[srow[k]], v1 = z2[srow[k + 1]];
        s0 += v0; s1 += v1;
    }
    if (k < end) s0 += z2[srow[k]];
    out[n] = fmaxf(fmaf(dis[n], s0 + s1, b2[0]), 0.0f);
}

// ---------- launch ----------
extern "C" void kernel_launch(void* const* d_in, const int* in_sizes, int n_in,
                              void* d_out, int out_size, void* d_ws, size_t ws_size,
                              hipStream_t stream) {
    const float* x  = (const float*)d_in[0];
    const int*   ei = (const int*)d_in[1];     // [2, E] int32: row then col
    const float* W1 = (const float*)d_in[2];
    const float* b1 = (const float*)d_in[3];
    const float* W2 = (const float*)d_in[4];
    const float* b2 = (const float*)d_in[5];
    float* out = (float*)d_out;

    const int* row = ei;
    const int* col = ei + NE;

    // workspace layout
    unsigned* packed     = (unsigned*)d_ws;            // NE
    unsigned* srow       = packed + NE;                // NE
    float2*   y2         = (float2*)(srow + NE);       // NN float2
    float*    dis        = (float*)(y2 + NN);          // NN
    float*    z2         = dis + NN;                   // NN
    int*      node_begin = (int*)(z2 + NN);            // NN+1
    int*      bcnt       = node_begin + NN + 1;        // NB
    int*      start      = bcnt + NB;                  // NB+1
    int*      cursor     = start + NB + 1;             // NB

    hipMemsetAsync(bcnt, 0, NB * sizeof(int), stream);

    hist_kernel   <<<256, 256, 0, stream>>>(col, bcnt);
    scan_kernel   <<<1, 512, 0, stream>>>(bcnt, start, cursor);
    reorder_kernel<<<NPB, 256, 0, stream>>>(row, col, cursor, packed);
    sortb_kernel  <<<NB, 256, 0, stream>>>(packed, start, (const float2*)x, srow,
                                           node_begin, dis, y2);
    conv1_kernel  <<<(NN + 127) / 128, 128, 0, stream>>>(srow, node_begin, y2, dis,
                                                         W1, b1, W2, z2);
    conv2_kernel  <<<(NN + 127) / 128, 128, 0, stream>>>(srow, node_begin, z2, dis, b2, out);
}